// Round 1
// 618.012 us; speedup vs baseline: 1.0517x; 1.0517x over previous
//
#include <hip/hip_runtime.h>
#include <hip/hip_bf16.h>

// LSTM: B=256, T=512, I=256, H=128 (4H=512 gates), then MLP 128->64->32->4.
// ROUND 9: fuse GEMM(chunk c+1) with LSTM(chunk c) in ONE kernel launch.
//   Blocks 0..63   : lstm role (recurrence, 64 steps, setprio(1))
//   Blocks 64..575 : gemm role (gx for the NEXT chunk, 512-thread tiles)
//   gx double-buffered (TC=64 -> 2 x 16.78 MB = same 33.55 MB footprint).
//   Timeline: G0; [L0||G1]; [L1||G2]; ... [L7]; head.  GEMM cost hidden.
//
//   gx gate-plane layout (unchanged):
//     idx(g,t,blk2,wj,L) = (((g*TC+t)*64 + blk2)*512) + wj*64 + L
//     blk2=batch>>2, j=gate&127, wj=j>>4, L=(j&15)*4+(batch&3).
//   lstm role: RB=4 rows/block, lane-spread activations (1 unit/thread),
//     W_hh static in VGPRs, h double-buffered LDS, HROW=144 (2-way only),
//     gx = 4 coalesced ushort loads/lane/step, depth-4 prefetch ring.

#define TC       64               // timesteps per chunk (halved for gx dbuf)
#define NCHUNK   8
#define BATCH    256
#define TSEQ     512
#define ISZ      256
#define HSZ      128
#define RB       4
#define NBLK     (BATCH / RB)     // 64 lstm blocks
#define NGB      (2 * TC * 4)     // 512 gemm blocks (2 batch-halves x TC x 4 planes)
#define HROW     144              // shorts; 72 dwords = 8 mod 32 -> 2-way only
#define GX_PER_T 131072           // gx elements per timestep (all 4 planes)
#define GXCH     ((size_t)TC * GX_PER_T)   // shorts per chunk gx buffer
#define STRT     32768            // per-plane step stride in shorts (64*512)
#define PF       4                // gx prefetch depth in steps

typedef __attribute__((ext_vector_type(8))) short short8;
typedef __attribute__((ext_vector_type(4))) float f32x4;

__device__ __forceinline__ void barrier_nodrain() {
    // s_barrier WITHOUT the compiler's vmcnt(0) drain: LDS consistency only.
    __asm__ __volatile__("s_waitcnt lgkmcnt(0)\n\ts_barrier" ::: "memory");
}
__device__ __forceinline__ void lds_fence() {
    // order this wave's LDS write->read (exchange buffer is wave-private)
    __asm__ __volatile__("s_waitcnt lgkmcnt(0)" ::: "memory");
}

__device__ __forceinline__ float fast_rcp(float x) {
    return __builtin_amdgcn_rcpf(x);
}
__device__ __forceinline__ float sigmoidf_(float x) {
    return fast_rcp(1.0f + __expf(-x));
}
__device__ __forceinline__ float tanhf_(float x) {
    float e = __expf(2.0f * x);               // inf-safe
    return 1.0f - 2.0f * fast_rcp(e + 1.0f);
}
__device__ __forceinline__ unsigned short f2bf(float x) {  // fp32 -> bf16 RNE
    union { float f; unsigned u; } v; v.f = x;
    unsigned r = v.u + 0x7fffu + ((v.u >> 16) & 1u);
    return (unsigned short)(r >> 16);
}
__device__ __forceinline__ float bf2f(unsigned short b) {
    union { unsigned u; float f; } v;
    v.u = ((unsigned)b) << 16;
    return v.f;
}
__device__ __forceinline__ unsigned packbf(float lo, float hi) {  // packed HW cvt
    __hip_bfloat162 h2 = __float22bfloat162_rn(make_float2(lo, hi));
    union { __hip_bfloat162 h; unsigned u; } v; v.h = h2;
    return v.u;
}

// ---------------------------------------------------------------------------
// Fused kernel. gxl = gx buffer the lstm role READS (chunk c, produced by the
// previous launch); gxg = gx buffer the gemm role WRITES (chunk c+1, t0).
__global__ __launch_bounds__(512, 2) void fused_kernel(
    const float* __restrict__ x, const float* __restrict__ Wih,
    const float* __restrict__ bih, const float* __restrict__ bhh,
    const float* __restrict__ Whh,
    const unsigned short* __restrict__ gxl, unsigned short* __restrict__ gxg,
    float* __restrict__ hc, int t0, int first, int run_lstm, int run_gemm)
{
    __shared__ __align__(16) char smem[32768];   // union of both roles' LDS
    const int tid  = threadIdx.x;
    const int w    = tid >> 6;
    const int lane = tid & 63;
    const int n    = lane & 15;
    const int quad = lane >> 4;

    if (blockIdx.x >= NBLK) {
        // ===================== GEMM role (gx for chunk c+1) =================
        if (!run_gemm) return;
        short* As = (short*)smem;            // [2][128*32] bf16, 16 KB
        short* Bs = (short*)(smem + 16384);  // [2][128*32] bf16, 16 KB

        const int gb = (int)blockIdx.x - NBLK;
        const int nt = gb & 3;               // gate plane
        const int mt = gb >> 2;              // 0 .. 2*TC-1
        const int tl = mt >> 1;              // timestep within chunk
        const int b0 = (mt & 1) * 128;       // batch half
        const int n0 = nt * 128;

        const int mq = w & 1;                // wave grid 2(m) x 4(n)
        const int nq = w >> 1;               // 0..3

        const int srow = tid >> 2;           // 0..127 staging row
        const int skh  = (tid & 3) * 8;      // float offset within 32-k slice
        const float* xrow = x + ((size_t)(b0 + srow) * TSEQ + (size_t)(t0 + tl)) * ISZ + skh;
        const float* wrow = Wih + (size_t)(n0 + srow) * ISZ + skh;

        f32x4 acc[4][2];
#pragma unroll
        for (int mi = 0; mi < 4; ++mi)
#pragma unroll
            for (int ni = 0; ni < 2; ++ni)
                acc[mi][ni] = (f32x4){0.f, 0.f, 0.f, 0.f};

        {   // preload k-slice 0
            float4 pa0 = *(const float4*)(xrow);
            float4 pa1 = *(const float4*)(xrow + 4);
            float4 pb0 = *(const float4*)(wrow);
            float4 pb1 = *(const float4*)(wrow + 4);
            *(uint4*)(&As[srow * 32 + skh]) =
                (uint4){packbf(pa0.x, pa0.y), packbf(pa0.z, pa0.w),
                        packbf(pa1.x, pa1.y), packbf(pa1.z, pa1.w)};
            *(uint4*)(&Bs[srow * 32 + skh]) =
                (uint4){packbf(pb0.x, pb0.y), packbf(pb0.z, pb0.w),
                        packbf(pb1.x, pb1.y), packbf(pb1.z, pb1.w)};
        }
        barrier_nodrain();

        for (int ks = 0; ks < 8; ++ks) {
            const int cur = (ks & 1) * 4096;
            const int nxt = 4096 - cur;

            float4 pa0, pa1, pb0, pb1;
            if (ks < 7) {
                pa0 = *(const float4*)(xrow + (ks + 1) * 32);
                pa1 = *(const float4*)(xrow + (ks + 1) * 32 + 4);
                pb0 = *(const float4*)(wrow + (ks + 1) * 32);
                pb1 = *(const float4*)(wrow + (ks + 1) * 32 + 4);
            }

            short8 af[4], bfr[2];
#pragma unroll
            for (int mi = 0; mi < 4; ++mi)
                af[mi] = *(const short8*)(&As[cur + (mq * 64 + mi * 16 + n) * 32 + quad * 8]);
#pragma unroll
            for (int ni = 0; ni < 2; ++ni)
                bfr[ni] = *(const short8*)(&Bs[cur + (nq * 32 + ni * 16 + n) * 32 + quad * 8]);
#pragma unroll
            for (int mi = 0; mi < 4; ++mi)
#pragma unroll
                for (int ni = 0; ni < 2; ++ni)
                    acc[mi][ni] = __builtin_amdgcn_mfma_f32_16x16x32_bf16(
                        af[mi], bfr[ni], acc[mi][ni], 0, 0, 0);

            if (ks < 7) {
                *(uint4*)(&As[nxt + srow * 32 + skh]) =
                    (uint4){packbf(pa0.x, pa0.y), packbf(pa0.z, pa0.w),
                            packbf(pa1.x, pa1.y), packbf(pa1.z, pa1.w)};
                *(uint4*)(&Bs[nxt + srow * 32 + skh]) =
                    (uint4){packbf(pb0.x, pb0.y), packbf(pb0.z, pb0.w),
                            packbf(pb1.x, pb1.y), packbf(pb1.z, pb1.w)};
            }
            barrier_nodrain();
        }

        // epilogue: bias + bf16, gate-plane layout, 8-B contiguous stores.
#pragma unroll
        for (int ni = 0; ni < 2; ++ni) {
            const int j    = nq * 32 + ni * 16 + n;
            const int gate = n0 + j;
            const float bias = bih[gate] + bhh[gate];
            const int wj = nq * 2 + ni;                       // j >> 4
#pragma unroll
            for (int mi = 0; mi < 4; ++mi) {
                const int bb   = b0 + mq * 64 + mi * 16 + quad * 4;
                const int blk2 = bb >> 2;
                const size_t idx = ((((size_t)nt * TC + tl) * 64 + blk2) * 512) +
                                   (size_t)wj * 64 + (size_t)n * 4;
                const unsigned lo = packbf(acc[mi][ni][0] + bias, acc[mi][ni][1] + bias);
                const unsigned hi = packbf(acc[mi][ni][2] + bias, acc[mi][ni][3] + bias);
                *(uint2*)(&gxg[idx]) = (uint2){lo, hi};
            }
        }
        return;
    }

    // ======================= LSTM role (recurrence, chunk c) ===============
    if (!run_lstm) return;
    __builtin_amdgcn_s_setprio(1);   // latency-critical chain wins issue arb
    short* h_lds  = (short*)smem;            // [2*RB*HROW] bf16 (2304 B)
    float* ex_lds = (float*)(smem + 2304);   // [8*256] per-wave exchange (8 KB)

    const int blk = (int)blockIdx.x;
    const int b0  = blk * RB;
    const int nb  = lane & 3;            // unit batch
    const int jl  = lane >> 2;           // unit j-local 0..15
    const int j   = 16 * w + jl;         // unit hidden index
    float* exw = ex_lds + w * 256;

    // static A-frags: W_hh[128g + 16w + n][32ks + 8quad + i] as bf16
    short8 Af[4][4];
#pragma unroll
    for (int g = 0; g < 4; ++g) {
        const float* row = Whh + (size_t)(128 * g + 16 * w + n) * HSZ + 8 * quad;
#pragma unroll
        for (int ks = 0; ks < 4; ++ks)
#pragma unroll
            for (int i = 0; i < 8; ++i)
                Af[g][ks][i] = (short)f2bf(row[32 * ks + i]);
    }

    // init unit state: every thread owns one (j, b) unit
    float c1 = 0.f, hl1 = 0.f;
    {
        unsigned short h0 = 0;
        if (!first) {
            c1 = hc[(size_t)BATCH * HSZ + (size_t)(b0 + nb) * HSZ + j];
            h0 = f2bf(hc[(size_t)(b0 + nb) * HSZ + j]);
        }
        *(unsigned short*)&h_lds[nb * HROW + j] = h0;   // buffer 0
    }

    // gx: 4 coalesced ushort loads per lane per step (one per gate plane)
    const unsigned short* gp[4];
#pragma unroll
    for (int g = 0; g < 4; ++g)
        gp[g] = gxl + (((size_t)g * TC) * 64 + blk) * 512 + (size_t)w * 64 + lane;

    unsigned short gq[PF][4];
#pragma unroll
    for (int d = 0; d < PF; ++d)
#pragma unroll
        for (int g = 0; g < 4; ++g)
            gq[d][g] = gp[g][(size_t)d * STRT];

    barrier_nodrain();

    for (int t = 0; t < TC; t += PF) {
#pragma unroll
        for (int u = 0; u < PF; ++u) {
            const int tt = t + u;
            const short* hb_r = h_lds + (u & 1) * (RB * HROW);
            short*       hb_w = h_lds + ((u & 1) ^ 1) * (RB * HROW);

            short8 Bf[4];
#pragma unroll
            for (int ks = 0; ks < 4; ++ks)
                Bf[ks] = *(const short8*)(&hb_r[nb * HROW + 32 * ks + 8 * quad]);

            // refill prefetch slot u for step tt+PF (clamped; value unused at end)
            const int tf = (tt + PF < TC) ? (tt + PF) : (TC - 1);
            unsigned short gnew[4];
#pragma unroll
            for (int g = 0; g < 4; ++g)
                gnew[g] = gp[g][(size_t)tf * STRT];

            // MFMAs: zero-C first, 4 independent chains
            f32x4 acc[4];
#pragma unroll
            for (int g = 0; g < 4; ++g)
                acc[g] = __builtin_amdgcn_mfma_f32_16x16x32_bf16(
                    Af[g][0], Bf[0], (f32x4){0.f, 0.f, 0.f, 0.f}, 0, 0, 0);
#pragma unroll
            for (int ks = 1; ks < 4; ++ks)
#pragma unroll
                for (int g = 0; g < 4; ++g)
                    acc[g] = __builtin_amdgcn_mfma_f32_16x16x32_bf16(
                        Af[g][ks], Bf[ks], acc[g], 0, 0, 0);

            // exchange: real cols (n<4) -> wave-private LDS, [g][b][j] fp32
            if (n < 4) {
#pragma unroll
                for (int g = 0; g < 4; ++g)
                    *(f32x4*)(&exw[(g * 4 + n) * 16 + 4 * quad]) = acc[g];
            }
            lds_fence();   // wave-internal write->read ordering

            const float d0 = exw[(0 * 4 + nb) * 16 + jl];
            const float d1 = exw[(1 * 4 + nb) * 16 + jl];
            const float d2 = exw[(2 * 4 + nb) * 16 + jl];
            const float d3 = exw[(3 * 4 + nb) * 16 + jl];

            const float ig = sigmoidf_(d0 + bf2f(gq[u][0]));
            const float fg = sigmoidf_(d1 + bf2f(gq[u][1]));
            const float gg = tanhf_(d2 + bf2f(gq[u][2]));
            const float og = sigmoidf_(d3 + bf2f(gq[u][3]));
            c1  = fg * c1 + ig * gg;
            hl1 = og * tanhf_(c1);
#pragma unroll
            for (int g = 0; g < 4; ++g) gq[u][g] = gnew[g];

            *(unsigned short*)&hb_w[nb * HROW + j] = f2bf(hl1);
            barrier_nodrain();
        }
    }

    hc[(size_t)(b0 + nb) * HSZ + j] = hl1;
    hc[(size_t)BATCH * HSZ + (size_t)(b0 + nb) * HSZ + j] = c1;
}

// ---------------------------------------------------------------------------
// MLP head: one block (64 threads) per batch row.
__global__ __launch_bounds__(64) void head_kernel(
    const float* __restrict__ hc,
    const float* __restrict__ W1, const float* __restrict__ b1,
    const float* __restrict__ W2, const float* __restrict__ b2,
    const float* __restrict__ W3, const float* __restrict__ b3,
    float* __restrict__ out)
{
    __shared__ float hs[HSZ];
    __shared__ float o1[64];
    __shared__ float o2[32];
    const int bidx = blockIdx.x;
    const int t = threadIdx.x;
    hs[t]      = hc[bidx * HSZ + t];
    hs[t + 64] = hc[bidx * HSZ + t + 64];
    __syncthreads();
    {
        float a = b1[t];
#pragma unroll 8
        for (int k = 0; k < HSZ; ++k) a += W1[t * HSZ + k] * hs[k];
        o1[t] = fmaxf(a, 0.0f);
    }
    __syncthreads();
    if (t < 32) {
        float a = b2[t];
#pragma unroll 8
        for (int k = 0; k < 64; ++k) a += W2[t * 64 + k] * o1[k];
        o2[t] = fmaxf(a, 0.0f);
    }
    __syncthreads();
    if (t < 4) {
        float a = b3[t];
#pragma unroll
        for (int k = 0; k < 32; ++k) a += W3[t * 32 + k] * o2[k];
        out[bidx * 4 + t] = a;
    }
}

// ---------------------------------------------------------------------------
extern "C" void kernel_launch(void* const* d_in, const int* in_sizes, int n_in,
                              void* d_out, int out_size, void* d_ws, size_t ws_size,
                              hipStream_t stream) {
    const float* x   = (const float*)d_in[0];
    const float* Wih = (const float*)d_in[1];
    const float* Whh = (const float*)d_in[2];
    const float* bih = (const float*)d_in[3];
    const float* bhh = (const float*)d_in[4];
    const float* W1  = (const float*)d_in[5];
    const float* b1  = (const float*)d_in[6];
    const float* W2  = (const float*)d_in[7];
    const float* b2  = (const float*)d_in[8];
    const float* W3  = (const float*)d_in[9];
    const float* b3  = (const float*)d_in[10];
    float* out = (float*)d_out;

    unsigned short* gx0 = (unsigned short*)d_ws;          // 16.78 MB bf16
    unsigned short* gx1 = gx0 + GXCH;                     // 16.78 MB bf16
    float* hc = (float*)((char*)d_ws + 2 * GXCH * sizeof(unsigned short)); // 256 KB

    // prologue: gemm chunk 0 -> gx0 (lstm blocks exit immediately)
    fused_kernel<<<dim3(NBLK + NGB), 512, 0, stream>>>(
        x, Wih, bih, bhh, Whh, gx0, gx0, hc, 0, 1, 0, 1);

    for (int c = 0; c < NCHUNK; ++c) {
        unsigned short* gl = (c & 1) ? gx1 : gx0;   // lstm reads chunk c
        unsigned short* gg = (c & 1) ? gx0 : gx1;   // gemm writes chunk c+1
        fused_kernel<<<dim3(NBLK + NGB), 512, 0, stream>>>(
            x, Wih, bih, bhh, Whh, gl, gg, hc,
            (c + 1) * TC, c == 0 ? 1 : 0, 1, (c + 1) < NCHUNK ? 1 : 0);
    }

    head_kernel<<<dim3(BATCH), 64, 0, stream>>>(hc, W1, b1, W2, b2, W3, b3, out);
}

// Round 2
// 555.364 us; speedup vs baseline: 1.1703x; 1.1128x over previous
//
#include <hip/hip_runtime.h>
#include <hip/hip_bf16.h>

// LSTM: B=256, T=512, I=256, H=128 (4H=512 gates), then MLP 128->64->32->4.
// ROUND 10:
//   * LSTM: LDS exchange removed — MFMA D-layout puts unit (j=lane>>2,
//     b=lane&3)'s gate in the lane's OWN acc[reg=(lane>>2)&3] (B cols
//     replicate mod 4). 2-level cndmask select replaces write+fence+read.
//   * LSTM: gq ring reloads consumed slot directly -> vmcnt wait lands PF
//     steps after issue, off the step critical path.
//   * GEMM: steady-state reads pre-converted bf16 x/Wih (no packbf storm,
//     half the staging bytes) -> less CU interference with LSTM role.
//   * Prologue launch = convert(x,Wih,Whh -> bf16) blocks || GEMM chunk 0
//     via fp32 path. ws >= 512 MiB (fill evidence), we use ~97 MiB.
//   Roles: blocks 0..63 lstm | 64..575 gemm | 576.. convert (prologue only).

#define TC       64
#define NCHUNK   8
#define BATCH    256
#define TSEQ     512
#define ISZ      256
#define HSZ      128
#define RB       4
#define NBLK     (BATCH / RB)     // 64 lstm blocks
#define NGB      (2 * TC * 4)     // 512 gemm blocks
#define HROW     144              // shorts; 72 dwords = 8 mod 32 -> 2-way only
#define GX_PER_T 131072           // gx elements per timestep (all 4 planes)
#define GXCH     ((size_t)TC * GX_PER_T)   // shorts per gx buffer
#define STRT     32768            // per-plane step stride in shorts (64*512)
#define PF       4                // gx prefetch depth in steps

#define XN       (BATCH * TSEQ * ISZ)   // 33554432 x elems
#define WIHN     (4 * HSZ * ISZ)        // 131072
#define WHHN     (4 * HSZ * HSZ)        // 65536
#define NCB      ((XN + WIHN + WHHN) / 8192)   // 4120 convert blocks

typedef __attribute__((ext_vector_type(8))) short short8;
typedef __attribute__((ext_vector_type(4))) float f32x4;

__device__ __forceinline__ void barrier_nodrain() {
    // s_barrier WITHOUT the compiler's vmcnt(0) drain: LDS consistency only.
    __asm__ __volatile__("s_waitcnt lgkmcnt(0)\n\ts_barrier" ::: "memory");
}

__device__ __forceinline__ float fast_rcp(float x) {
    return __builtin_amdgcn_rcpf(x);
}
__device__ __forceinline__ float sigmoidf_(float x) {
    return fast_rcp(1.0f + __expf(-x));
}
__device__ __forceinline__ float tanhf_(float x) {
    float e = __expf(2.0f * x);               // inf-safe
    return 1.0f - 2.0f * fast_rcp(e + 1.0f);
}
__device__ __forceinline__ unsigned short f2bf(float x) {  // fp32 -> bf16 RNE
    union { float f; unsigned u; } v; v.f = x;
    unsigned r = v.u + 0x7fffu + ((v.u >> 16) & 1u);
    return (unsigned short)(r >> 16);
}
__device__ __forceinline__ float bf2f(unsigned short b) {
    union { unsigned u; float f; } v;
    v.u = ((unsigned)b) << 16;
    return v.f;
}
__device__ __forceinline__ unsigned packbf(float lo, float hi) {  // packed HW cvt
    __hip_bfloat162 h2 = __float22bfloat162_rn(make_float2(lo, hi));
    union { __hip_bfloat162 h; unsigned u; } v; v.h = h2;
    return v.u;
}
__device__ __forceinline__ float sel4(f32x4 v, int r) {   // v[r], 3 cndmask
    float s01 = (r & 1) ? v[1] : v[0];
    float s23 = (r & 1) ? v[3] : v[2];
    return (r & 2) ? s23 : s01;
}

// ---------------------------------------------------------------------------
__global__ __launch_bounds__(512, 2) void fused_kernel(
    const float* __restrict__ x, const float* __restrict__ Wih,
    const float* __restrict__ bih, const float* __restrict__ bhh,
    const float* __restrict__ Whh,
    const unsigned short* __restrict__ gxl, unsigned short* __restrict__ gxg,
    float* __restrict__ hc,
    unsigned short* __restrict__ xb, unsigned short* __restrict__ wihb,
    unsigned short* __restrict__ whhb,
    int t0, int first, int run_lstm, int run_gemm, int use_xbf, int run_conv)
{
    __shared__ __align__(16) char smem[32768];
    const int tid  = threadIdx.x;
    const int w    = tid >> 6;
    const int lane = tid & 63;
    const int n    = lane & 15;
    const int quad = lane >> 4;

    if (blockIdx.x >= NBLK + NGB) {
        // ===================== CONVERT role (prologue only) =================
        if (!run_conv) return;
        const int cb = (int)blockIdx.x - (NBLK + NGB);
        const size_t e0 = ((size_t)cb * 512 + tid) * 16;
        const float* s; unsigned short* d;
        if (e0 < (size_t)XN)              { s = x + e0;                d = xb + e0; }
        else if (e0 < (size_t)(XN + WIHN)){ s = Wih + (e0 - XN);       d = wihb + (e0 - XN); }
        else                              { s = Whh + (e0 - XN - WIHN); d = whhb + (e0 - XN - WIHN); }
        float4 f0 = *(const float4*)(s);
        float4 f1 = *(const float4*)(s + 4);
        float4 f2 = *(const float4*)(s + 8);
        float4 f3 = *(const float4*)(s + 12);
        *(uint4*)(d)     = (uint4){packbf(f0.x, f0.y), packbf(f0.z, f0.w),
                                   packbf(f1.x, f1.y), packbf(f1.z, f1.w)};
        *(uint4*)(d + 8) = (uint4){packbf(f2.x, f2.y), packbf(f2.z, f2.w),
                                   packbf(f3.x, f3.y), packbf(f3.z, f3.w)};
        return;
    }

    if (blockIdx.x >= NBLK) {
        // ===================== GEMM role (gx for chunk at t0) ===============
        if (!run_gemm) return;
        short* As = (short*)smem;            // [2][128*32] bf16, 16 KB
        short* Bs = (short*)(smem + 16384);  // [2][128*32] bf16, 16 KB

        const int gb = (int)blockIdx.x - NBLK;
        const int nt = gb & 3;               // gate plane
        const int mt = gb >> 2;
        const int tl = mt >> 1;              // timestep within chunk
        const int b0 = (mt & 1) * 128;       // batch half
        const int n0 = nt * 128;

        const int mq = w & 1;                // wave grid 2(m) x 4(n)
        const int nq = w >> 1;

        const int srow = tid >> 2;           // 0..127 staging row
        const int skh  = (tid & 3) * 8;      // elem offset within 32-k slice

        f32x4 acc[4][2];
#pragma unroll
        for (int mi = 0; mi < 4; ++mi)
#pragma unroll
            for (int ni = 0; ni < 2; ++ni)
                acc[mi][ni] = (f32x4){0.f, 0.f, 0.f, 0.f};

        if (use_xbf) {
            // -------- bf16 staging: pure vector load -> LDS store ----------
            const unsigned short* xr = xb + ((size_t)(b0 + srow) * TSEQ + (size_t)(t0 + tl)) * ISZ + skh;
            const unsigned short* wr = wihb + (size_t)(n0 + srow) * ISZ + skh;
            *(short8*)(&As[srow * 32 + skh]) = *(const short8*)(xr);
            *(short8*)(&Bs[srow * 32 + skh]) = *(const short8*)(wr);
            barrier_nodrain();
            for (int ks = 0; ks < 8; ++ks) {
                const int cur = (ks & 1) * 4096;
                const int nxt = 4096 - cur;
                short8 va, vb;
                if (ks < 7) {
                    va = *(const short8*)(xr + (ks + 1) * 32);
                    vb = *(const short8*)(wr + (ks + 1) * 32);
                }
                short8 af[4], bfr[2];
#pragma unroll
                for (int mi = 0; mi < 4; ++mi)
                    af[mi] = *(const short8*)(&As[cur + (mq * 64 + mi * 16 + n) * 32 + quad * 8]);
#pragma unroll
                for (int ni = 0; ni < 2; ++ni)
                    bfr[ni] = *(const short8*)(&Bs[cur + (nq * 32 + ni * 16 + n) * 32 + quad * 8]);
#pragma unroll
                for (int mi = 0; mi < 4; ++mi)
#pragma unroll
                    for (int ni = 0; ni < 2; ++ni)
                        acc[mi][ni] = __builtin_amdgcn_mfma_f32_16x16x32_bf16(
                            af[mi], bfr[ni], acc[mi][ni], 0, 0, 0);
                if (ks < 7) {
                    *(short8*)(&As[nxt + srow * 32 + skh]) = va;
                    *(short8*)(&Bs[nxt + srow * 32 + skh]) = vb;
                }
                barrier_nodrain();
            }
        } else {
            // -------- fp32 staging (prologue chunk 0 only) -----------------
            const float* xrow = x + ((size_t)(b0 + srow) * TSEQ + (size_t)(t0 + tl)) * ISZ + skh;
            const float* wrow = Wih + (size_t)(n0 + srow) * ISZ + skh;
            {
                float4 pa0 = *(const float4*)(xrow);
                float4 pa1 = *(const float4*)(xrow + 4);
                float4 pb0 = *(const float4*)(wrow);
                float4 pb1 = *(const float4*)(wrow + 4);
                *(uint4*)(&As[srow * 32 + skh]) =
                    (uint4){packbf(pa0.x, pa0.y), packbf(pa0.z, pa0.w),
                            packbf(pa1.x, pa1.y), packbf(pa1.z, pa1.w)};
                *(uint4*)(&Bs[srow * 32 + skh]) =
                    (uint4){packbf(pb0.x, pb0.y), packbf(pb0.z, pb0.w),
                            packbf(pb1.x, pb1.y), packbf(pb1.z, pb1.w)};
            }
            barrier_nodrain();
            for (int ks = 0; ks < 8; ++ks) {
                const int cur = (ks & 1) * 4096;
                const int nxt = 4096 - cur;
                float4 pa0, pa1, pb0, pb1;
                if (ks < 7) {
                    pa0 = *(const float4*)(xrow + (ks + 1) * 32);
                    pa1 = *(const float4*)(xrow + (ks + 1) * 32 + 4);
                    pb0 = *(const float4*)(wrow + (ks + 1) * 32);
                    pb1 = *(const float4*)(wrow + (ks + 1) * 32 + 4);
                }
                short8 af[4], bfr[2];
#pragma unroll
                for (int mi = 0; mi < 4; ++mi)
                    af[mi] = *(const short8*)(&As[cur + (mq * 64 + mi * 16 + n) * 32 + quad * 8]);
#pragma unroll
                for (int ni = 0; ni < 2; ++ni)
                    bfr[ni] = *(const short8*)(&Bs[cur + (nq * 32 + ni * 16 + n) * 32 + quad * 8]);
#pragma unroll
                for (int mi = 0; mi < 4; ++mi)
#pragma unroll
                    for (int ni = 0; ni < 2; ++ni)
                        acc[mi][ni] = __builtin_amdgcn_mfma_f32_16x16x32_bf16(
                            af[mi], bfr[ni], acc[mi][ni], 0, 0, 0);
                if (ks < 7) {
                    *(uint4*)(&As[nxt + srow * 32 + skh]) =
                        (uint4){packbf(pa0.x, pa0.y), packbf(pa0.z, pa0.w),
                                packbf(pa1.x, pa1.y), packbf(pa1.z, pa1.w)};
                    *(uint4*)(&Bs[nxt + srow * 32 + skh]) =
                        (uint4){packbf(pb0.x, pb0.y), packbf(pb0.z, pb0.w),
                                packbf(pb1.x, pb1.y), packbf(pb1.z, pb1.w)};
                }
                barrier_nodrain();
            }
        }

        // epilogue: bias + bf16, gate-plane layout, 8-B contiguous stores.
#pragma unroll
        for (int ni = 0; ni < 2; ++ni) {
            const int j    = nq * 32 + ni * 16 + n;
            const int gate = n0 + j;
            const float bias = bih[gate] + bhh[gate];
            const int wj = nq * 2 + ni;                       // j >> 4
#pragma unroll
            for (int mi = 0; mi < 4; ++mi) {
                const int bb   = b0 + mq * 64 + mi * 16 + quad * 4;
                const int blk2 = bb >> 2;
                const size_t idx = ((((size_t)nt * TC + tl) * 64 + blk2) * 512) +
                                   (size_t)wj * 64 + (size_t)n * 4;
                const unsigned lo = packbf(acc[mi][ni][0] + bias, acc[mi][ni][1] + bias);
                const unsigned hi = packbf(acc[mi][ni][2] + bias, acc[mi][ni][3] + bias);
                *(uint2*)(&gxg[idx]) = (uint2){lo, hi};
            }
        }
        return;
    }

    // ======================= LSTM role (recurrence) =========================
    if (!run_lstm) return;
    __builtin_amdgcn_s_setprio(1);   // latency-critical chain wins issue arb
    short* h_lds = (short*)smem;     // [2*RB*HROW] bf16 (2304 B)

    const int blk  = (int)blockIdx.x;
    const int b0   = blk * RB;
    const int nb   = lane & 3;           // unit batch
    const int jl   = lane >> 2;          // unit j-local 0..15
    const int j    = 16 * w + jl;        // unit hidden index
    const int rsel = jl & 3;             // D-reg holding this unit's gate

    // static A-frags straight from pre-converted bf16 Whh
    short8 Af[4][4];
#pragma unroll
    for (int g = 0; g < 4; ++g) {
        const unsigned short* rowb = whhb + (size_t)(128 * g + 16 * w + n) * HSZ + 8 * quad;
#pragma unroll
        for (int ks = 0; ks < 4; ++ks)
            Af[g][ks] = *(const short8*)(rowb + 32 * ks);
    }

    // init unit state: every thread owns one (j, b) unit
    float c1 = 0.f, hl1 = 0.f;
    {
        unsigned short h0 = 0;
        if (!first) {
            c1 = hc[(size_t)BATCH * HSZ + (size_t)(b0 + nb) * HSZ + j];
            h0 = f2bf(hc[(size_t)(b0 + nb) * HSZ + j]);
        }
        *(unsigned short*)&h_lds[nb * HROW + j] = h0;   // buffer 0
    }

    // gx: 4 coalesced ushort loads per lane per step (one per gate plane)
    const unsigned short* gp[4];
#pragma unroll
    for (int g = 0; g < 4; ++g)
        gp[g] = gxl + (((size_t)g * TC) * 64 + blk) * 512 + (size_t)w * 64 + lane;

    unsigned short gq[PF][4];
#pragma unroll
    for (int d = 0; d < PF; ++d)
#pragma unroll
        for (int g = 0; g < 4; ++g)
            gq[d][g] = gp[g][(size_t)d * STRT];

    barrier_nodrain();

    for (int t = 0; t < TC; t += PF) {
#pragma unroll
        for (int u = 0; u < PF; ++u) {
            const int tt = t + u;
            const short* hb_r = h_lds + (u & 1) * (RB * HROW);
            short*       hb_w = h_lds + ((u & 1) ^ 1) * (RB * HROW);

            short8 Bf[4];
#pragma unroll
            for (int ks = 0; ks < 4; ++ks)
                Bf[ks] = *(const short8*)(&hb_r[nb * HROW + 32 * ks + 8 * quad]);

            // MFMAs: zero-C first, 4 independent chains
            f32x4 acc[4];
#pragma unroll
            for (int g = 0; g < 4; ++g)
                acc[g] = __builtin_amdgcn_mfma_f32_16x16x32_bf16(
                    Af[g][0], Bf[0], (f32x4){0.f, 0.f, 0.f, 0.f}, 0, 0, 0);
#pragma unroll
            for (int ks = 1; ks < 4; ++ks)
#pragma unroll
                for (int g = 0; g < 4; ++g)
                    acc[g] = __builtin_amdgcn_mfma_f32_16x16x32_bf16(
                        Af[g][ks], Bf[ks], acc[g], 0, 0, 0);

            // in-lane gate extract: unit (jl,nb)'s value is THIS lane's
            // acc[g][rsel] (D row = 4*quad+reg = jl, D col batch = nb).
            const float s0 = sel4(acc[0], rsel) + bf2f(gq[u][0]);
            const float s1 = sel4(acc[1], rsel) + bf2f(gq[u][1]);
            const float s2 = sel4(acc[2], rsel) + bf2f(gq[u][2]);
            const float s3 = sel4(acc[3], rsel) + bf2f(gq[u][3]);

            // reload ring slot u (just consumed) for step tt+PF; vmcnt wait
            // for these loads lands PF steps from now.
            const int tf = (tt + PF < TC) ? (tt + PF) : (TC - 1);
#pragma unroll
            for (int g = 0; g < 4; ++g)
                gq[u][g] = gp[g][(size_t)tf * STRT];

            const float ig = sigmoidf_(s0);
            const float fg = sigmoidf_(s1);
            const float gg = tanhf_(s2);
            const float og = sigmoidf_(s3);
            c1  = fg * c1 + ig * gg;
            hl1 = og * tanhf_(c1);

            *(unsigned short*)&hb_w[nb * HROW + j] = f2bf(hl1);
            barrier_nodrain();
        }
    }

    hc[(size_t)(b0 + nb) * HSZ + j] = hl1;
    hc[(size_t)BATCH * HSZ + (size_t)(b0 + nb) * HSZ + j] = c1;
}

// ---------------------------------------------------------------------------
// MLP head: one block (64 threads) per batch row.
__global__ __launch_bounds__(64) void head_kernel(
    const float* __restrict__ hc,
    const float* __restrict__ W1, const float* __restrict__ b1,
    const float* __restrict__ W2, const float* __restrict__ b2,
    const float* __restrict__ W3, const float* __restrict__ b3,
    float* __restrict__ out)
{
    __shared__ float hs[HSZ];
    __shared__ float o1[64];
    __shared__ float o2[32];
    const int bidx = blockIdx.x;
    const int t = threadIdx.x;
    hs[t]      = hc[bidx * HSZ + t];
    hs[t + 64] = hc[bidx * HSZ + t + 64];
    __syncthreads();
    {
        float a = b1[t];
#pragma unroll 8
        for (int k = 0; k < HSZ; ++k) a += W1[t * HSZ + k] * hs[k];
        o1[t] = fmaxf(a, 0.0f);
    }
    __syncthreads();
    if (t < 32) {
        float a = b2[t];
#pragma unroll 8
        for (int k = 0; k < 64; ++k) a += W2[t * 64 + k] * o1[k];
        o2[t] = fmaxf(a, 0.0f);
    }
    __syncthreads();
    if (t < 4) {
        float a = b3[t];
#pragma unroll
        for (int k = 0; k < 32; ++k) a += W3[t * 32 + k] * o2[k];
        out[bidx * 4 + t] = a;
    }
}

// ---------------------------------------------------------------------------
extern "C" void kernel_launch(void* const* d_in, const int* in_sizes, int n_in,
                              void* d_out, int out_size, void* d_ws, size_t ws_size,
                              hipStream_t stream) {
    const float* x   = (const float*)d_in[0];
    const float* Wih = (const float*)d_in[1];
    const float* Whh = (const float*)d_in[2];
    const float* bih = (const float*)d_in[3];
    const float* bhh = (const float*)d_in[4];
    const float* W1  = (const float*)d_in[5];
    const float* b1  = (const float*)d_in[6];
    const float* W2  = (const float*)d_in[7];
    const float* b2  = (const float*)d_in[8];
    const float* W3  = (const float*)d_in[9];
    const float* b3  = (const float*)d_in[10];
    float* out = (float*)d_out;

    const size_t GXB = GXCH * sizeof(unsigned short);          // 16.78 MB
    unsigned short* gx0 = (unsigned short*)d_ws;
    unsigned short* gx1 = (unsigned short*)((char*)d_ws + GXB);
    float* hc = (float*)((char*)d_ws + 2 * GXB);               // 256 KB
    unsigned short* xb   = (unsigned short*)((char*)d_ws + 2 * GXB + 262144);
    unsigned short* wihb = xb + (size_t)XN;
    unsigned short* whhb = wihb + WIHN;

    // prologue: convert x/Wih/Whh -> bf16 || gemm chunk 0 via fp32 path
    fused_kernel<<<dim3(NBLK + NGB + NCB), 512, 0, stream>>>(
        x, Wih, bih, bhh, Whh, gx0, gx0, hc, xb, wihb, whhb,
        0, 1, 0, 1, 0, 1);

    for (int c = 0; c < NCHUNK; ++c) {
        unsigned short* gl = (c & 1) ? gx1 : gx0;   // lstm reads chunk c
        unsigned short* gg = (c & 1) ? gx0 : gx1;   // gemm writes chunk c+1
        fused_kernel<<<dim3(NBLK + NGB), 512, 0, stream>>>(
            x, Wih, bih, bhh, Whh, gl, gg, hc, xb, wihb, whhb,
            (c + 1) * TC, c == 0 ? 1 : 0, 1, (c + 1) < NCHUNK ? 1 : 0, 1, 0);
    }

    head_kernel<<<dim3(BATCH), 64, 0, stream>>>(hc, W1, b1, W2, b2, W3, b3, out);
}